// Round 2
// baseline (79.985 us; speedup 1.0000x reference)
//
#include <hip/hip_runtime.h>

// out[b, t, c] = data[(index[b] + t) % cycle_len][c]
// B=2048, L=720, C=64 (fp32). Pure write-streaming kernel (377 MB out).
//
// R2 strategy: NO LDS. The 43 KB data table is L1/L2-resident (every block
// on a CU reads the same bytes), so read it directly through the cache:
//  - no 43 KB LDS allocation -> 8 blocks/CU co-resident (32 waves/CU),
//    and 2048 blocks = exactly 8 per CU -> single residency round, no
//    ceil(8/3) quantization loss of the LDS version.
//  - no staging loop + __syncthreads() prologue per block.
// Row index advances incrementally (+16 mod cycle_len per step): one integer
// mod per thread total. Output stores are nontemporal (streaming, never
// re-read) so write-allocate doesn't evict the hot table from L2.

using f4 = __attribute__((ext_vector_type(4))) float;

constexpr int CCH   = 64;        // channels
constexpr int C4    = CCH / 4;   // float4 per row = 16
constexpr int BLOCK = 256;

__global__ __launch_bounds__(BLOCK) void recurrent_cycle_kernel(
    const int* __restrict__ index,
    const f4*  __restrict__ data4,   // [cycle_len][C4]
    f4*        __restrict__ out4,    // [B][L][C4]
    int L, int cycle_len)
{
    const int tid = threadIdx.x;
    const int b   = blockIdx.x;

    const int idx = index[b];
    f4* outb = out4 + (size_t)b * (size_t)L * C4;
    const int n = L * C4;               // 720*16 = 11520 float4 per batch

    // Thread tid starts at flat float4 position tid: t = tid/16, c4 = tid%16.
    const int t0 = tid >> 4;
    const int c4 = tid & (C4 - 1);
    int row = (idx + t0) % cycle_len;   // the only integer mod
    const int rstep = (BLOCK / C4) % cycle_len;  // 16

    #pragma unroll 3
    for (int p = tid; p < n; p += BLOCK) {
        f4 v = data4[row * C4 + c4];    // L1/L2 hit (table is 43 KB, hot)
        __builtin_nontemporal_store(v, &outb[p]);
        row += rstep;
        if (row >= cycle_len) row -= cycle_len;
    }
}

extern "C" void kernel_launch(void* const* d_in, const int* in_sizes, int n_in,
                              void* d_out, int out_size, void* d_ws, size_t ws_size,
                              hipStream_t stream) {
    // setup_inputs order: index [B] int32, length (scalar, unused — derived
    // from out_size), data [cycle_len*64] fp32.
    const int*   index = (const int*)d_in[0];
    const float* data  = (const float*)d_in[2];

    const int B         = in_sizes[0];
    const int cycle_len = in_sizes[2] / CCH;      // 168
    const int L         = out_size / (B * CCH);   // 720

    recurrent_cycle_kernel<<<B, BLOCK, 0, stream>>>(
        index, (const f4*)data, (f4*)d_out, L, cycle_len);
}

// Round 3
// 76.087 us; speedup vs baseline: 1.0512x; 1.0512x over previous
//
#include <hip/hip_runtime.h>

// out[b, t, c] = data[(index[b] + t) % cycle_len][c]
// B=2048, L=720, C=64 (fp32). Pure write-streaming kernel (377 MB out).
//
// R3: register-resident values, fill-kernel-shaped store loop.
// Per thread (c4 = tid%16 fixed, t stepping by 16 per iter), the row index
// sequence (r0 + 16p) mod 168 has period 168/gcd(168,16) = 21. So each
// thread needs only 21 distinct float4 values (84 VGPRs). Preload them once
// (fully unrolled -> static register indices), then emit 45 fully-unrolled
// PURE stores: no loads, no dependency chain in the steady state — the same
// structure as rocclr's fillBuffer, which sustains 7.0 TB/s on this chip.

using f4 = __attribute__((ext_vector_type(4))) float;

constexpr int CCH   = 64;        // channels
constexpr int C4    = CCH / 4;   // float4 per row = 16
constexpr int BLOCK = 256;
constexpr int CYC   = 168;       // fast-path cycle length
constexpr int RSTEP = BLOCK / C4;            // 16 rows per iteration
constexpr int NR    = 21;        // CYC / gcd(CYC, RSTEP) distinct rows/thread

template <int ITERS>
__global__ __launch_bounds__(BLOCK) void rc_fast(
    const int* __restrict__ index,
    const f4*  __restrict__ data4,   // [CYC][C4]
    f4*        __restrict__ out4,    // [B][L][C4]
    int L)
{
    const int tid = threadIdx.x;
    const int b   = blockIdx.x;

    const int t0 = tid >> 4;
    const int c4 = tid & (C4 - 1);
    const int r0 = (index[b] + t0) % CYC;

    // Preload the 21 distinct rows this thread will ever store.
    f4 v[NR];
    #pragma unroll
    for (int j = 0; j < NR; ++j) {
        int row = r0 + RSTEP * j;               // < 168 + 320 = 488
        if (row >= 2 * CYC) row -= 2 * CYC;
        else if (row >= CYC) row -= CYC;
        v[j] = data4[row * C4 + c4];
    }

    // Pure-store steady state. p compile-time -> v[p % NR] is a static
    // register reference (no scratch).
    f4* outb = out4 + (size_t)b * (size_t)L * C4 + tid;
    #pragma unroll
    for (int p = 0; p < ITERS; ++p) {
        outb[p * BLOCK] = v[p % NR];
    }
}

// Generic fallback (R1-style, correct for any shape).
__global__ __launch_bounds__(BLOCK) void rc_generic(
    const int* __restrict__ index,
    const f4*  __restrict__ data4,
    f4*        __restrict__ out4,
    int L, int cycle_len)
{
    const int tid = threadIdx.x;
    const int b   = blockIdx.x;
    const int idx = index[b];
    f4* outb = out4 + (size_t)b * (size_t)L * C4;
    const int n  = L * C4;
    const int t0 = tid >> 4;
    const int c4 = tid & (C4 - 1);
    int row = (idx + t0) % cycle_len;
    const int rstep = RSTEP % cycle_len;
    for (int p = tid; p < n; p += BLOCK) {
        outb[p] = data4[row * C4 + c4];
        row += rstep;
        if (row >= cycle_len) row -= cycle_len;
    }
}

extern "C" void kernel_launch(void* const* d_in, const int* in_sizes, int n_in,
                              void* d_out, int out_size, void* d_ws, size_t ws_size,
                              hipStream_t stream) {
    // setup_inputs order: index [B] int32, length scalar (derived), data fp32.
    const int*   index = (const int*)d_in[0];
    const float* data  = (const float*)d_in[2];

    const int B         = in_sizes[0];
    const int cycle_len = in_sizes[2] / CCH;      // 168
    const int L         = out_size / (B * CCH);   // 720

    if (cycle_len == CYC && L == 720) {
        rc_fast<720 * C4 / BLOCK><<<B, BLOCK, 0, stream>>>(
            index, (const f4*)data, (f4*)d_out, L);
    } else {
        rc_generic<<<B, BLOCK, 0, stream>>>(
            index, (const f4*)data, (f4*)d_out, L, cycle_len);
    }
}

// Round 4
// 67.057 us; speedup vs baseline: 1.1928x; 1.1347x over previous
//
#include <hip/hip_runtime.h>

// out[b, t, c] = data[(index[b] + t) % cycle_len][c]
// B=2048, L=720, C=64 (fp32). 377 MB pure write stream.
//
// R4: GLOBAL GRID-STRIDE store order (fillBuffer-shaped). R1-R3 proved the
// limiter is not reads/occupancy/dependencies -- all landed at ~77us (4.95
// TB/s) while rocclr fillBufferAligned hits 7.0 TB/s on the same chip. The
// one remaining structural difference is store order: block-per-b opens 2048
// independent 180 KB write streams (DRAM page thrash), while grid-stride
// sweeps ONE contiguous ~4 MB window across the buffer. This kernel mimics
// the fill's order; per-element index math uses compile-time-constant
// divisors (magic mul) and L1-resident table/index loads.

using f4 = __attribute__((ext_vector_type(4))) float;

constexpr int CCH   = 64;         // channels
constexpr int C4    = CCH / 4;    // float4 per row = 16
constexpr int BLOCK = 256;
constexpr unsigned GRIDB = 1024;  // fast-path grid: 4 blocks/CU, 4 MB window

// Fast path: all divisors compile-time.
template <unsigned ROWF4, unsigned CYC, unsigned ITERS>
__global__ __launch_bounds__(BLOCK) void rc_stride(
    const int* __restrict__ index,
    const f4*  __restrict__ data4,   // [CYC][C4]
    f4*        __restrict__ out4)    // flat [B*L*C4]
{
    const unsigned G = GRIDB * BLOCK;            // 262144 threads
    unsigned p = blockIdx.x * BLOCK + threadIdx.x;
    #pragma unroll 4
    for (unsigned i = 0; i < ITERS; ++i, p += G) {
        unsigned b   = p / ROWF4;                // magic mul
        unsigned q   = p - b * ROWF4;
        unsigned t   = q >> 4;
        unsigned c4  = q & (C4 - 1);
        unsigned row = ((unsigned)index[b] + t) % CYC;   // magic mul
        out4[p] = data4[row * C4 + c4];          // L1-hit (43 KB table)
    }
}

// Generic fallback (R1-style, correct for any shape).
__global__ __launch_bounds__(BLOCK) void rc_generic(
    const int* __restrict__ index,
    const f4*  __restrict__ data4,
    f4*        __restrict__ out4,
    int L, int cycle_len)
{
    const int tid = threadIdx.x;
    const int b   = blockIdx.x;
    const int idx = index[b];
    f4* outb = out4 + (size_t)b * (size_t)L * C4;
    const int n  = L * C4;
    const int t0 = tid >> 4;
    const int c4 = tid & (C4 - 1);
    int row = (idx + t0) % cycle_len;
    const int rstep = (BLOCK / C4) % cycle_len;
    for (int p = tid; p < n; p += BLOCK) {
        outb[p] = data4[row * C4 + c4];
        row += rstep;
        if (row >= cycle_len) row -= cycle_len;
    }
}

extern "C" void kernel_launch(void* const* d_in, const int* in_sizes, int n_in,
                              void* d_out, int out_size, void* d_ws, size_t ws_size,
                              hipStream_t stream) {
    // setup_inputs order: index [B] int32, length scalar (derived), data fp32.
    const int*   index = (const int*)d_in[0];
    const float* data  = (const float*)d_in[2];

    const int B         = in_sizes[0];
    const int cycle_len = in_sizes[2] / CCH;      // 168
    const int L         = out_size / (B * CCH);   // 720

    if (B == 2048 && L == 720 && cycle_len == 168) {
        // total f4 = 2048*720*16 = 23,592,960 = (1024*256) * 90 exactly
        rc_stride<720 * C4, 168, 90><<<GRIDB, BLOCK, 0, stream>>>(
            index, (const f4*)data, (f4*)d_out);
    } else {
        rc_generic<<<B, BLOCK, 0, stream>>>(
            index, (const f4*)data, (f4*)d_out, L, cycle_len);
    }
}